// Round 7
// baseline (639.660 us; speedup 1.0000x reference)
//
#include <hip/hip_runtime.h>
#include <hip/hip_bf16.h>

typedef __hip_bfloat16 bf16;
typedef __attribute__((ext_vector_type(8))) short bf16x8;   // 8 bf16 = 4 VGPRs
typedef __attribute__((ext_vector_type(4))) float f32x4;
typedef __attribute__((ext_vector_type(4))) int int4v;

#define AS1 __attribute__((address_space(1)))
#define AS3 __attribute__((address_space(3)))

#define MDIM 8192   // B*S
#define NDIM 4096   // D_OUT
#define KDIM 4096   // D_IN
#define SCALING 2.0f
#define NT (KDIM / 64)

// ---------------------------------------------------------------------------
// prep: fused fold + convert, register-reuse version (NO LDS).  At its BW
// floor (~65 us): two structurally different variants (r4 LDS-tiled, r5
// register) gave identical totals.  DO NOT MODIFY.
// ---------------------------------------------------------------------------
__global__ __launch_bounds__(256) void prep(
    const float* __restrict__ W, const float* __restrict__ lA,
    const float* __restrict__ lB, const float* __restrict__ delta,
    const int* __restrict__ mask, bf16* __restrict__ Weff,
    const float* __restrict__ X, bf16* __restrict__ Xb)
{
    const int bid = blockIdx.x;
    const int tid = threadIdx.x;

    if (bid < 2048) {
        // ---- fold: block = 16 o-rows x 512 d-cols ----
        const int ob    = (bid >> 3) * 16;
        const int db    = (bid & 7) * 512;
        const int obase = ob + (tid >> 6) * 4;
        const int dc    = db + (tid & 63) * 8;

        float Bo[4][16];
#pragma unroll
        for (int oo = 0; oo < 4; ++oo)
#pragma unroll
            for (int r = 0; r < 16; ++r)
                Bo[oo][r] = lB[(obase + oo) * 16 + r];

        float lor[4][8];
#pragma unroll
        for (int oo = 0; oo < 4; ++oo)
#pragma unroll
            for (int e = 0; e < 8; ++e) lor[oo][e] = 0.f;

#pragma unroll
        for (int r = 0; r < 16; ++r) {
            f32x4 aa = *(const f32x4*)(lA + (size_t)r * KDIM + dc);
            f32x4 ab = *(const f32x4*)(lA + (size_t)r * KDIM + dc + 4);
#pragma unroll
            for (int oo = 0; oo < 4; ++oo)
#pragma unroll
                for (int e = 0; e < 4; ++e) {
                    lor[oo][e]     += Bo[oo][r] * aa[e];
                    lor[oo][e + 4] += Bo[oo][r] * ab[e];
                }
        }

#pragma unroll
        for (int oo = 0; oo < 4; ++oo) {
            const size_t base = (size_t)(obase + oo) * KDIM + dc;

            f32x4 wa  = *(const f32x4*)(W + base);
            f32x4 wb  = *(const f32x4*)(W + base + 4);
            f32x4 da  = *(const f32x4*)(delta + base);
            f32x4 db4 = *(const f32x4*)(delta + base + 4);

            int mk[8];
            *(int4v*)(mk)     = *(const int4v*)(mask + base);
            *(int4v*)(mk + 4) = *(const int4v*)(mask + base + 4);

            int4v ov4;
            bf16* ov = (bf16*)&ov4;
#pragma unroll
            for (int e = 0; e < 8; ++e) {
                float w = (e < 4) ? wa[e] : wb[e - 4];
                float d = (e < 4) ? da[e] : db4[e - 4];
                float a = w + SCALING * lor[oo][e];
                if (mk[e]) a += d;
                ov[e] = __float2bfloat16(a);
            }
            *(int4v*)(Weff + base) = ov4;
        }
    } else {
        // ---- convert X (grid-stride, 8 iters/thread) ----
        const size_t nchunk = (size_t)MDIM * KDIM / 8;
        for (size_t c = (size_t)(bid - 2048) * 256 + tid; c < nchunk;
             c += (size_t)2048 * 256) {
            const size_t i = c * 8;
            f32x4 a = *(const f32x4*)(X + i);
            f32x4 b = *(const f32x4*)(X + i + 4);
            int4v ov4;
            bf16* ov = (bf16*)&ov4;
#pragma unroll
            for (int e = 0; e < 4; ++e) {
                ov[e]     = __float2bfloat16(a[e]);
                ov[e + 4] = __float2bfloat16(b[e]);
            }
            *(int4v*)(Xb + i) = ov4;
        }
    }
}

// ---------------------------------------------------------------------------
// GEMM, double-buffered one-barrier-per-tile ("minimum 2-phase") version.
// Same 128x128 tile / BK=64 / swizzle / fragment math / epilogue as the
// proven 269-us kernel; the ONLY structural change is the loop skeleton:
//   per tile: STAGE(t+1 -> other buf)  [issued FIRST]
//             ds_read + 32 MFMA (t)    [stage latency hides under this]
//             __syncthreads()          [vmcnt(0) drain now nearly free]
// vs the old stage -> sync(drain exposed) -> compute -> sync.
// 512 threads (8 waves, 2Mx4N, wave-tile 64x32) so 2 blocks/CU still gives
// 16 waves/CU.  LDS 64 KB (2 x (A 16K + B 16K)).  VGPR ~95 <= 128.
// Barrier-uniformity audit (r6): the only conditional is block-uniform;
// buffer write/read hazards separated by the per-tile __syncthreads().
// ---------------------------------------------------------------------------
__global__ __launch_bounds__(512, 4) void gemm_bf16(
    const bf16* __restrict__ X, const bf16* __restrict__ Wt,
    const float* __restrict__ bias, float* __restrict__ out)
{
    __shared__ bf16 As[2][128 * 64];   // 32 KB
    __shared__ bf16 Bs[2][128 * 64];   // 32 KB

    const int tid  = threadIdx.x;
    const int lane = tid & 63;
    const int wvb  = tid & ~63;
    const int wave = tid >> 6;         // 0..7
    const int wm   = wave & 1;         // 2 M-waves -> m-offset wm*64
    const int wn   = wave >> 1;        // 4 N-waves -> n-offset wn*32
    const int quad = lane >> 4;
    const int l16  = lane & 15;

    const int bn = blockIdx.x * 128;
    const int bm = blockIdx.y * 128;

    f32x4 acc[4][2];
#pragma unroll
    for (int i = 0; i < 4; ++i)
#pragma unroll
        for (int j = 0; j < 2; ++j)
            acc[i][j] = (f32x4){0.f, 0.f, 0.f, 0.f};

    // stage tile kt into buffer buf: 2 gload_lds for A + 2 for B (512 thr)
#define STAGE(buf, kt)                                                         \
    {                                                                          \
        const int k0_ = (kt) * 64;                                             \
        _Pragma("unroll")                                                      \
        for (int gi = 0; gi < 2; ++gi) {                                       \
            const int c  = gi * 512 + tid;                                     \
            const int m  = c >> 3;                                             \
            const int kc = (c & 7) ^ (m & 7);                                  \
            const int cb = gi * 512 + wvb;                                     \
            __builtin_amdgcn_global_load_lds(                                  \
                (const AS1 void*)(X + (size_t)(bm + m) * KDIM + k0_ + kc * 8), \
                (AS3 void*)(As[buf] + cb * 8), 16, 0, 0);                      \
            __builtin_amdgcn_global_load_lds(                                  \
                (const AS1 void*)(Wt + (size_t)(bn + m) * KDIM + k0_ + kc * 8),\
                (AS3 void*)(Bs[buf] + cb * 8), 16, 0, 0);                      \
        }                                                                      \
    }

    // Prologue: tile 0 into buf 0, drain, sync.
    STAGE(0, 0)
    __syncthreads();

    for (int kt = 0; kt < NT; ++kt) {
        const int cur = kt & 1;

        // Issue next tile's staging FIRST -> flies under this tile's MFMAs.
        if (kt + 1 < NT) STAGE(cur ^ 1, kt + 1)

        const bf16* Ac = As[cur];
        const bf16* Bc = Bs[cur];
#pragma unroll
        for (int ks = 0; ks < 2; ++ks) {
            bf16x8 af[4], bfr[2];
#pragma unroll
            for (int i = 0; i < 4; ++i) {
                const int m   = wm * 64 + i * 16 + l16;
                const int kca = (ks * 4 + quad) ^ (m & 7);
                af[i] = *(const bf16x8*)(Ac + m * 64 + kca * 8);
            }
#pragma unroll
            for (int j = 0; j < 2; ++j) {
                const int n   = wn * 32 + j * 16 + l16;
                const int kcb = (ks * 4 + quad) ^ (n & 7);
                bfr[j] = *(const bf16x8*)(Bc + n * 64 + kcb * 8);
            }
#pragma unroll
            for (int i = 0; i < 4; ++i)
#pragma unroll
                for (int j = 0; j < 2; ++j)
                    acc[i][j] = __builtin_amdgcn_mfma_f32_16x16x32_bf16(
                        af[i], bfr[j], acc[i][j], 0, 0, 0);
        }

        // ONE barrier per tile: drains the (long-issued) stage loads and
        // ensures all waves finished reading buf[cur] before it's reused.
        __syncthreads();
    }

    // Epilogue.  C/D layout: col = lane&15, row = quad*4 + reg.
    float bv[2];
#pragma unroll
    for (int j = 0; j < 2; ++j)
        bv[j] = bias[bn + wn * 32 + j * 16 + l16];

#pragma unroll
    for (int i = 0; i < 4; ++i) {
        const int mg = bm + wm * 64 + i * 16 + quad * 4;
#pragma unroll
        for (int j = 0; j < 2; ++j) {
            const int ng = bn + wn * 32 + j * 16 + l16;
#pragma unroll
            for (int r = 0; r < 4; ++r)
                out[(size_t)(mg + r) * NDIM + ng] = acc[i][j][r] + bv[j];
        }
    }
#undef STAGE
}

// ---------------------------------------------------------------------------
// Fallback GEMM (fp32 X) — used only if ws can't fit the bf16 copy of X.
// ---------------------------------------------------------------------------
__global__ __launch_bounds__(256, 3) void gemm_f32(
    const float* __restrict__ X, const bf16* __restrict__ Wt,
    const float* __restrict__ bias, float* __restrict__ out)
{
    __shared__ float Asf[128 * 64];  // 32 KB
    __shared__ bf16  Bs[128 * 64];   // 16 KB

    const int tid  = threadIdx.x;
    const int lane = tid & 63;
    const int wave = tid >> 6;
    const int wmf  = wave & 1;
    const int wnf  = wave >> 1;
    const int quad = lane >> 4;
    const int l16  = lane & 15;

    const int bn = blockIdx.x * 128;
    const int bm = blockIdx.y * 128;
    const int cwave = tid & ~63;

    f32x4 acc[4][4];
#pragma unroll
    for (int i = 0; i < 4; ++i)
#pragma unroll
        for (int j = 0; j < 4; ++j)
            acc[i][j] = (f32x4){0.f, 0.f, 0.f, 0.f};

    for (int kt = 0; kt < KDIM / 64; ++kt) {
        const int k0 = kt * 64;
        if (kt) __syncthreads();
#pragma unroll
        for (int j = 0; j < 8; ++j) {
            const int c  = j * 256 + tid;
            const int m  = c >> 4;
            const int kc = (c & 15) ^ (m & 15);
            const int cb = j * 256 + cwave;
            __builtin_amdgcn_global_load_lds(
                (const AS1 void*)(X + (size_t)(bm + m) * KDIM + k0 + kc * 4),
                (AS3 void*)(Asf + cb * 4), 16, 0, 0);
        }
#pragma unroll
        for (int j = 0; j < 4; ++j) {
            const int c  = j * 256 + tid;
            const int m  = c >> 3;
            const int kc = (c & 7) ^ (m & 7);
            const int cb = j * 256 + cwave;
            __builtin_amdgcn_global_load_lds(
                (const AS1 void*)(Wt + (size_t)(bn + m) * KDIM + k0 + kc * 8),
                (AS3 void*)(Bs + cb * 8), 16, 0, 0);
        }
        __syncthreads();

#pragma unroll
        for (int ks = 0; ks < 2; ++ks) {
            bf16x8 af[4], bfr[4];
#pragma unroll
            for (int i = 0; i < 4; ++i) {
                const int m  = wmf * 64 + i * 16 + l16;
                const int k2 = (ks * 4 + quad) * 2;
                f32x4 lo = *(const f32x4*)(Asf + m * 64 + ((k2     ^ (m & 15)) * 4));
                f32x4 hi = *(const f32x4*)(Asf + m * 64 + (((k2+1) ^ (m & 15)) * 4));
                bf16 tmp[8];
#pragma unroll
                for (int e = 0; e < 4; ++e) {
                    tmp[e]     = __float2bfloat16(lo[e]);
                    tmp[e + 4] = __float2bfloat16(hi[e]);
                }
                af[i] = *(const bf16x8*)tmp;

                const int n   = wnf * 64 + i * 16 + l16;
                const int kcb = (ks * 4 + quad) ^ (n & 7);
                bfr[i] = *(const bf16x8*)(Bs + n * 64 + kcb * 8);
            }
#pragma unroll
            for (int i = 0; i < 4; ++i)
#pragma unroll
                for (int j = 0; j < 4; ++j)
                    acc[i][j] = __builtin_amdgcn_mfma_f32_16x16x32_bf16(
                        af[i], bfr[j], acc[i][j], 0, 0, 0);
        }
    }

    float bv[4];
#pragma unroll
    for (int j = 0; j < 4; ++j)
        bv[j] = bias[bn + wnf * 64 + j * 16 + l16];

#pragma unroll
    for (int i = 0; i < 4; ++i) {
        const int mg = bm + wmf * 64 + i * 16 + quad * 4;
#pragma unroll
        for (int j = 0; j < 4; ++j) {
            const int ng = bn + wnf * 64 + j * 16 + l16;
#pragma unroll
            for (int r = 0; r < 4; ++r)
                out[(size_t)(mg + r) * NDIM + ng] = acc[i][j][r] + bv[j];
        }
    }
}

// ---------------------------------------------------------------------------
extern "C" void kernel_launch(void* const* d_in, const int* in_sizes, int n_in,
                              void* d_out, int out_size, void* d_ws, size_t ws_size,
                              hipStream_t stream)
{
    const float* x     = (const float*)d_in[0];
    const float* W     = (const float*)d_in[1];
    const float* b     = (const float*)d_in[2];
    const float* lA    = (const float*)d_in[3];
    const float* lB    = (const float*)d_in[4];
    const float* delta = (const float*)d_in[5];
    const int*   mask  = (const int*)d_in[6];
    float* out = (float*)d_out;

    bf16* Weff = (bf16*)d_ws;                                     // 33.5 MB
    bf16* Xb   = (bf16*)((char*)d_ws + (size_t)NDIM * KDIM * 2);  // 67 MB

    const size_t need = (size_t)NDIM * KDIM * 2 + (size_t)MDIM * KDIM * 2;

    if (ws_size >= need) {
        prep<<<dim3(4096), 256, 0, stream>>>(
            W, lA, lB, delta, mask, Weff, x, Xb);
        gemm_bf16<<<dim3(NDIM / 128, MDIM / 128), 512, 0, stream>>>(
            Xb, Weff, b, out);
    } else {
        prep<<<dim3(2048), 256, 0, stream>>>(   // fold only
            W, lA, lB, delta, mask, Weff, x, Xb);
        gemm_f32<<<dim3(NDIM / 128, MDIM / 128), 256, 0, stream>>>(
            x, Weff, b, out);
    }
}